// Round 1
// baseline (364.027 us; speedup 1.0000x reference)
//
#include <hip/hip_runtime.h>
#include <math.h>

#define EPS_F 1e-6f

// One wave (64 lanes) per row; 4 rows per 256-thread block.
// Each lane holds 32 row elements in registers (8 x float4, lane-stride
// coalesced: 1 KiB contiguous per wave per load instruction).
__global__ __launch_bounds__(256) void focal_row_kernel(
    const float* __restrict__ x, const int* __restrict__ tgt,
    const float* __restrict__ cw, float* __restrict__ partial,
    int B, int C)
{
    const int wave = threadIdx.x >> 6;
    const int lane = threadIdx.x & 63;
    const int row  = blockIdx.x * 4 + wave;

    float val = 0.0f;
    if (row < B) {
        const float4* xr = (const float4*)(x + (size_t)row * (size_t)C);
        float v[32];
        float m = -3.4e38f;
#pragma unroll
        for (int i = 0; i < 8; ++i) {
            float4 f = xr[lane + 64 * i];
            v[4 * i + 0] = f.x; v[4 * i + 1] = f.y;
            v[4 * i + 2] = f.z; v[4 * i + 3] = f.w;
            m = fmaxf(m, fmaxf(fmaxf(f.x, f.y), fmaxf(f.z, f.w)));
        }
        // wave-wide max (64 lanes)
#pragma unroll
        for (int off = 32; off > 0; off >>= 1)
            m = fmaxf(m, __shfl_xor(m, off, 64));

        float s = 0.0f;
#pragma unroll
        for (int i = 0; i < 32; ++i) s += __expf(v[i] - m);
        // wave-wide sum
#pragma unroll
        for (int off = 32; off > 0; off >>= 1)
            s += __shfl_xor(s, off, 64);

        if (lane == 0) {
            const int t = tgt[row];
            const float xt = x[(size_t)row * (size_t)C + (size_t)t];     // L1/L2 hit
            const float xd = x[(size_t)row * (size_t)C + (size_t)(C-1)]; // L1/L2 hit
            const float inv_s = 1.0f / s;
            const float pt = __expf(xt - m) * inv_s;
            const float pd = __expf(xd - m) * inv_s;
            const float w  = cw[t];
            const float log_pt   = __logf(pt == 0.0f ? pt + EPS_F : pt);
            const float pt2      = (pt == 1.0f) ? (1.0f - EPS_F) * pt : pt;
            const float log_1mpt = __logf(1.0f - pt2);
            val = w * (-log_pt * (1.0f - pd) - log_1mpt * pd);
        }
    }

    // combine the 4 per-wave row losses into one partial per block
    __shared__ float sm[4];
    if (lane == 0) sm[wave] = val;
    __syncthreads();
    if (threadIdx.x == 0)
        partial[blockIdx.x] = sm[0] + sm[1] + sm[2] + sm[3];
}

// Single-block reduction of the block partials; writes final scalar.
__global__ __launch_bounds__(256) void reduce_partials_kernel(
    const float* __restrict__ p, float* __restrict__ out, int n, float invB)
{
    float s = 0.0f;
    for (int i = threadIdx.x; i < n; i += 256) s += p[i];
#pragma unroll
    for (int off = 32; off > 0; off >>= 1)
        s += __shfl_xor(s, off, 64);
    __shared__ float sm[4];
    const int wave = threadIdx.x >> 6;
    const int lane = threadIdx.x & 63;
    if (lane == 0) sm[wave] = s;
    __syncthreads();
    if (threadIdx.x == 0)
        out[0] = (sm[0] + sm[1] + sm[2] + sm[3]) * invB;
}

extern "C" void kernel_launch(void* const* d_in, const int* in_sizes, int n_in,
                              void* d_out, int out_size, void* d_ws, size_t ws_size,
                              hipStream_t stream)
{
    const float* x   = (const float*)d_in[0];   // (B, C) fp32 logits
    const int*   tgt = (const int*)d_in[1];     // (B,) int32 targets
    const float* cw  = (const float*)d_in[2];   // (C,) fp32 class weights

    const int B = in_sizes[1];                  // 32768
    const int C = in_sizes[2];                  // 2048
    float* out = (float*)d_out;
    float* partial = (float*)d_ws;              // nblocks floats of scratch

    const int nblocks = (B + 3) / 4;            // 4 rows per block
    focal_row_kernel<<<nblocks, 256, 0, stream>>>(x, tgt, cw, partial, B, C);
    reduce_partials_kernel<<<1, 256, 0, stream>>>(partial, out, nblocks,
                                                  1.0f / (float)B);
}